// Round 2
// baseline (718.859 us; speedup 1.0000x reference)
//
#include <hip/hip_runtime.h>
#include <hip/hip_bf16.h>
#include <hip/hip_fp16.h>
#include <cstdint>
#include <cstddef>

// Problem constants
#define NF 128        // F
#define N_EDGES 100000
#define N_ANGLES 400000
#define N_CRYST 512
#define KDIM 320      // 2F + A
#define TWOF 256
#define EPS_LN 1e-5f
#define INV_SQRT_2 0.70710678118654752440f
#define CAP 32        // max angles per source edge (Poisson lambda=4; P(>=24)*1e5 ~ 1e-12)

typedef short short8 __attribute__((ext_vector_type(8)));
typedef float floatx4 __attribute__((ext_vector_type(4)));

// ---------------- helpers ----------------
__device__ inline unsigned short f2bf(float x) {
    __hip_bfloat16 b = __float2bfloat16(x);
    return *reinterpret_cast<unsigned short*>(&b);
}
__device__ inline float bf2f(__hip_bfloat16 b) { return __bfloat162float(b); }
__device__ inline float bfbits2f(unsigned short u) {
    unsigned int v = ((unsigned int)u) << 16;
    return __uint_as_float(v);
}

__device__ inline uint4 cvt8(float4 a, float4 b) {
    __hip_bfloat162 p0 = __float22bfloat162_rn(make_float2(a.x, a.y));
    __hip_bfloat162 p1 = __float22bfloat162_rn(make_float2(a.z, a.w));
    __hip_bfloat162 p2 = __float22bfloat162_rn(make_float2(b.x, b.y));
    __hip_bfloat162 p3 = __float22bfloat162_rn(make_float2(b.z, b.w));
    uint4 r;
    r.x = *reinterpret_cast<unsigned int*>(&p0);
    r.y = *reinterpret_cast<unsigned int*>(&p1);
    r.z = *reinterpret_cast<unsigned int*>(&p2);
    r.w = *reinterpret_cast<unsigned int*>(&p3);
    return r;
}

// ---------------- kernel 1: segment boundaries (sorted crystal_angle_index) ----------------
__global__ void seg_bounds(const int* __restrict__ seg, int* __restrict__ seg_start) {
    int s = blockIdx.x * blockDim.x + threadIdx.x;
    if (s > N_CRYST) return;
    if (s == N_CRYST) { seg_start[N_CRYST] = N_ANGLES; return; }
    int lo = 0, hi = N_ANGLES;
    while (lo < hi) { int mid = (lo + hi) >> 1; if (seg[mid] < s) lo = mid + 1; else hi = mid; }
    seg_start[s] = lo;
}

// ---------------- kernel 2: fused gather + GEMM + segment-stats via bf16 MFMA (v3) ----------------
// 128 rows x ALL 256 cols per block, 512 threads = 8 waves.
// v3 pipeline: double-buffered LDS + depth-2 register ring + raw s_barrier with
// lgkmcnt(0)-only waits. Global loads for K-tile k+3 are issued at iter k and stay
// in flight across barriers (no vmcnt(0) drain -> counted vmcnt at consumption).
// Epilogue additionally computes per-segment sum/sumsq from the in-register f32
// accumulators (rows sorted by segment -> a block spans <=~2 segments), removing
// the separate 205 MB seg_stats pass.
__global__ __launch_bounds__(512) void gemm_gather_mfma(
    const float* __restrict__ angle_fea,      // N_ANGLES x 64
    const float* __restrict__ nbr_fea,        // N_EDGES x 128
    const int*   __restrict__ angle_nbr_idx,  // N_ANGLES x 2
    const float* __restrict__ W_full,         // 256 x 320 (row-major)
    const int*   __restrict__ cai,            // sorted segment id per row
    float* __restrict__ segSum, float* __restrict__ segSumSq,
    __hip_bfloat16* __restrict__ hout)        // N_ANGLES x 256
{
    __shared__ uint4 X_lds[2][512];    // 2 x (128 rows x 32 k bf16) = 16 KB, swizzled
    __shared__ uint4 W_lds[2][1024];   // 2 x (256 n    x 32 k bf16) = 32 KB, swizzled

    const int tid  = threadIdx.x;
    const int row0 = blockIdx.x * 128;    // 3125 blocks, exact

    // X staging: 512 chunks (16B bf16 = 8 k-elems), 1 per thread.
    const int xm = tid >> 2;
    const int xk = ((tid & 3) ^ ((xm >> 1) & 3)) * 8;
    const int p0 = angle_nbr_idx[(size_t)(row0 + xm) * 2 + 0];
    const int p1 = angle_nbr_idx[(size_t)(row0 + xm) * 2 + 1];
    // W staging: 1024 chunks, 2 per thread.
    int wn[2], wk[2];
    #pragma unroll
    for (int it = 0; it < 2; ++it) {
        int tau = it * 512 + tid;
        wn[it] = tau >> 2;
        wk[it] = ((tau & 3) ^ ((wn[it] >> 1) & 3)) * 8;
    }

    const int wave = tid >> 6, lane = tid & 63;
    const int wrow = (wave & 1) * 64;      // m-quadrant (2 of 128)
    const int wcol = (wave >> 1) * 64;     // n-quadrant (4 of 256)
    const int rl   = lane & 15, kgrp = lane >> 4;
    const int fragoff = (kgrp ^ ((rl >> 1) & 3)) * 16;  // swizzled byte offset

    floatx4 acc[4][4];
    #pragma unroll
    for (int i = 0; i < 4; ++i)
        #pragma unroll
        for (int j = 0; j < 4; ++j)
            acc[i][j] = (floatx4){0.f, 0.f, 0.f, 0.f};

    // depth-2 register ring (fully unrolled loop -> all indices compile-time)
    float4 xr[2][2];
    float4 wr[2][4];
    auto loadX = [&](int kbase, int s) {
        const float* src;
        if (kbase < 64)       src = angle_fea + (size_t)(row0 + xm) * 64 + kbase + xk;
        else if (kbase < 192) src = nbr_fea + (size_t)p0 * 128 + (kbase - 64) + xk;
        else                  src = nbr_fea + (size_t)p1 * 128 + (kbase - 192) + xk;
        xr[s][0] = ((const float4*)src)[0];
        xr[s][1] = ((const float4*)src)[1];
    };
    auto loadW = [&](int kbase, int s) {
        const float* s0 = W_full + (size_t)wn[0] * KDIM + kbase + wk[0];
        wr[s][0] = ((const float4*)s0)[0];
        wr[s][1] = ((const float4*)s0)[1];
        const float* s1 = W_full + (size_t)wn[1] * KDIM + kbase + wk[1];
        wr[s][2] = ((const float4*)s1)[0];
        wr[s][3] = ((const float4*)s1)[1];
    };

    // prologue: k=0 -> slot0, k=1 -> slot1; stage k=0 into buf0; k=2 -> slot0
    loadX(0, 0);  loadW(0, 0);
    loadX(32, 1); loadW(32, 1);
    {
        uint4 xc  = cvt8(xr[0][0], xr[0][1]);
        uint4 wc0 = cvt8(wr[0][0], wr[0][1]);
        uint4 wc1 = cvt8(wr[0][2], wr[0][3]);
        X_lds[0][tid]       = xc;
        W_lds[0][tid]       = wc0;
        W_lds[0][512 + tid] = wc1;
    }
    loadX(64, 0); loadW(64, 0);
    asm volatile("s_waitcnt lgkmcnt(0)" ::: "memory");
    __builtin_amdgcn_s_barrier();

    #pragma unroll
    for (int k = 0; k < 10; ++k) {
        const int cur = k & 1, nxt = (k + 1) & 1;
        const char* Xb = (const char*)X_lds[cur];
        const char* Wb = (const char*)W_lds[cur];
        short8 wf[4], xf[4];
        #pragma unroll
        for (int i = 0; i < 4; ++i)
            wf[i] = *(const short8*)(Wb + (size_t)(wcol + i * 16 + rl) * 64 + fragoff);
        #pragma unroll
        for (int j = 0; j < 4; ++j)
            xf[j] = *(const short8*)(Xb + (size_t)(wrow + j * 16 + rl) * 64 + fragoff);
        if (k < 9) {
            // cvt slot[nxt] (holds k+1's data; compiler emits counted vmcnt wait)
            uint4 xc  = cvt8(xr[nxt][0], xr[nxt][1]);
            uint4 wc0 = cvt8(wr[nxt][0], wr[nxt][1]);
            uint4 wc1 = cvt8(wr[nxt][2], wr[nxt][3]);
            X_lds[nxt][tid]       = xc;
            W_lds[nxt][tid]       = wc0;
            W_lds[nxt][512 + tid] = wc1;
            if (k + 3 <= 9) {               // issue loads for k+3 into the freed slot
                loadX((k + 3) * 32, nxt);
                loadW((k + 3) * 32, nxt);
            }
        }
        #pragma unroll
        for (int i = 0; i < 4; ++i)
            #pragma unroll
            for (int j = 0; j < 4; ++j)
                acc[i][j] = __builtin_amdgcn_mfma_f32_16x16x32_bf16(wf[i], xf[j], acc[i][j], 0, 0, 0);
        if (k < 9) {
            asm volatile("s_waitcnt lgkmcnt(0)" ::: "memory");  // my ds ops done (no vmcnt drain)
            __builtin_amdgcn_s_barrier();
        }
    }

    // epilogue 1: store h. D[n][m] -> h[m][n]; lane holds 4 consecutive n per (i,j)
    unsigned short* hp = reinterpret_cast<unsigned short*>(hout);
    #pragma unroll
    for (int j = 0; j < 4; ++j) {
        size_t r = (size_t)(row0 + wrow + j * 16 + rl);
        #pragma unroll
        for (int i = 0; i < 4; ++i) {
            int c = wcol + i * 16 + kgrp * 4;
            floatx4 v = acc[i][j];
            uint2 pk;
            pk.x = (unsigned int)f2bf(v[0]) | ((unsigned int)f2bf(v[1]) << 16);
            pk.y = (unsigned int)f2bf(v[2]) | ((unsigned int)f2bf(v[3]) << 16);
            *reinterpret_cast<uint2*>(hp + r * TWOF + c) = pk;
        }
    }

    // epilogue 2: fused per-segment sum/sumsq from f32 accumulators.
    // lane's rows: r(j) = row0 + wrow + j*16 + rl; lane's cols: wcol + i*16 + kgrp*4 + g
    float* red = (float*)&X_lds[0][0];   // reuse LDS: 2 halves x 256 cols x {S,Q} = 4 KB
    int sj[4];
    #pragma unroll
    for (int j = 0; j < 4; ++j) sj[j] = cai[row0 + wrow + j * 16 + rl];
    const int sA = cai[row0], sB = cai[row0 + 127];   // uniform across block
    for (int s = sA; s <= sB; ++s) {
        float S[16], Q[16];
        #pragma unroll
        for (int t = 0; t < 16; ++t) { S[t] = 0.f; Q[t] = 0.f; }
        #pragma unroll
        for (int j = 0; j < 4; ++j) {
            float msk = (sj[j] == s) ? 1.f : 0.f;
            #pragma unroll
            for (int i = 0; i < 4; ++i)
                #pragma unroll
                for (int g = 0; g < 4; ++g) {
                    float v = acc[i][j][g] * msk;
                    S[i * 4 + g] += v;
                    Q[i * 4 + g] += v * v;
                }
        }
        // reduce over the 16-lane rl group (lane bits 0..3)
        #pragma unroll
        for (int t = 0; t < 16; ++t) {
            #pragma unroll
            for (int d = 1; d < 16; d <<= 1) {
                S[t] += __shfl_xor(S[t], d, 64);
                Q[t] += __shfl_xor(Q[t], d, 64);
            }
        }
        __syncthreads();   // red region free / previous s-iter consumed
        if (rl == 0) {
            #pragma unroll
            for (int i = 0; i < 4; ++i)
                #pragma unroll
                for (int g = 0; g < 4; ++g) {
                    int col = wcol + i * 16 + kgrp * 4 + g;
                    red[((wave & 1) * 256 + col) * 2 + 0] = S[i * 4 + g];
                    red[((wave & 1) * 256 + col) * 2 + 1] = Q[i * 4 + g];
                }
        }
        __syncthreads();
        if (tid < 256) {
            int col = tid;
            float Ss = red[col * 2]     + red[(256 + col) * 2];
            float Qs = red[col * 2 + 1] + red[(256 + col) * 2 + 1];
            atomicAdd(&segSum[(size_t)s * TWOF + col], Ss);
            atomicAdd(&segSumSq[(size_t)s * TWOF + col], Qs);
        }
    }
}

// ---------------- kernel 4: finalize mean / rsqrt(var+eps) in place ----------------
__global__ __launch_bounds__(256) void seg_finalize(
    const int* __restrict__ seg_start,
    float* __restrict__ segSum, float* __restrict__ segSumSq)
{
    int seg = blockIdx.x;
    int j = threadIdx.x;
    float cnt = (float)max(seg_start[seg + 1] - seg_start[seg], 1);
    float inv = 1.0f / cnt;
    float mean = segSum[seg * TWOF + j] * inv;
    float var  = segSumSq[seg * TWOF + j] * inv - mean * mean;
    segSum[seg * TWOF + j]   = mean;
    segSumSq[seg * TWOF + j] = rsqrtf(var + EPS_LN);
}

// ---------------- kernel 5: per-angle normalize + LN(core) + gate -> msg store + slot list ----------------
// v2: lane owns cols {2l, 2l+1} of each half -> all loads/stores are 4-8B vector ops
// (2x fewer transactions than the scalar-bf16 version). Wave-wide reductions are
// unchanged (mapping-agnostic). msg written as f16 in place over the dead first
// 256B of the h row; one int atomic per row registers it in the source edge's slot list.
__global__ __launch_bounds__(256) void angle_msg(
    __hip_bfloat16* __restrict__ h,
    const int* __restrict__ seg_idx,
    const int* __restrict__ angle_nbr_idx,
    const float* __restrict__ segMean, const float* __restrict__ segScale,
    const float* __restrict__ cn_gamma, const float* __restrict__ cn_beta,
    const float* __restrict__ ln_g, const float* __restrict__ ln_b,
    const float* __restrict__ w_mask,
    int* __restrict__ slot_cnt, int* __restrict__ slots)
{
    int row  = blockIdx.x * 4 + (threadIdx.x >> 6);
    int lane = threadIdx.x & 63;
    int seg  = seg_idx[row];
    int src  = angle_nbr_idx[(size_t)row * 2];

    unsigned short* hr = reinterpret_cast<unsigned short*>(h + (size_t)row * TWOF);
    const int c0 = 2 * lane;                       // core cols c0, c0+1; filter cols 128+c0, 128+c0+1
    unsigned int ucore = ((const unsigned int*)hr)[lane];
    unsigned int ufilt = ((const unsigned int*)hr)[lane + 64];

    float2 m0 = *(const float2*)&segMean[seg * TWOF + c0];
    float2 s0 = *(const float2*)&segScale[seg * TWOF + c0];
    float2 m1 = *(const float2*)&segMean[seg * TWOF + 128 + c0];
    float2 s1 = *(const float2*)&segScale[seg * TWOF + 128 + c0];
    float2 g0 = *(const float2*)&cn_gamma[c0];
    float2 b0 = *(const float2*)&cn_beta[c0];
    float2 g1 = *(const float2*)&cn_gamma[128 + c0];
    float2 b1 = *(const float2*)&cn_beta[128 + c0];

    float y0 = (bfbits2f((unsigned short)(ucore & 0xffffu)) - m0.x) * s0.x * g0.x + b0.x;
    float y1 = (bfbits2f((unsigned short)(ucore >> 16))     - m0.y) * s0.y * g0.y + b0.y;
    float y2 = (bfbits2f((unsigned short)(ufilt & 0xffffu)) - m1.x) * s1.x * g1.x + b1.x;
    float y3 = (bfbits2f((unsigned short)(ufilt >> 16))     - m1.y) * s1.y * g1.y + b1.y;

    float sum = y0 + y1, ssq = y0 * y0 + y1 * y1;
    #pragma unroll
    for (int o = 32; o > 0; o >>= 1) { sum += __shfl_xor(sum, o, 64); ssq += __shfl_xor(ssq, o, 64); }
    float mu  = sum * (1.f / 128.f);
    float var = ssq * (1.f / 128.f) - mu * mu;
    float rs  = rsqrtf(var + EPS_LN);
    float2 lg = *(const float2*)&ln_g[c0];
    float2 lb = *(const float2*)&ln_b[c0];
    float ln0 = (y0 - mu) * rs * lg.x + lb.x;
    float ln1 = (y1 - mu) * rs * lg.y + lb.y;
    float si0 = ln0 / (1.f + __expf(-ln0));
    float si1 = ln1 / (1.f + __expf(-ln1));
    float2 wm = *(const float2*)&w_mask[c0];
    float gp = y2 * wm.x + y3 * wm.y;
    #pragma unroll
    for (int o = 32; o > 0; o >>= 1) gp += __shfl_xor(gp, o, 64);
    float gate = 1.f / (1.f + __expf(-gp));

    // msg (f16) over this lane's own 4 bytes of the row -> no cross-lane WAR hazard
    __half2 hh = __floats2half2_rn(gate * si0, gate * si1);
    ((unsigned int*)hr)[lane] = *reinterpret_cast<unsigned int*>(&hh);

    if (lane == 0) {
        int k = atomicAdd(&slot_cnt[src], 1);
        if (k < CAP) slots[(size_t)src * CAP + k] = row;
    }
}

// ---------------- kernel 6: edge MLP via bf16 MFMA ----------------
// 64 edges/block, 256 threads (4 waves). Phase 0 gathers the per-edge msg rows
// (avg 4, f16, 256B each) and sums in registers. Then LN2 + 2x residual MLP
// entirely in LDS/MFMA. Wave w owns edge rows w*16..w*16+15 end-to-end.
#define MT 64
#define XBS 136
#define H1S 72
#define W1S 136
#define W2S 72
__global__ __launch_bounds__(256) void edge_mlp_mfma(
    const __hip_bfloat16* __restrict__ hmsg,   // msg rows live in h buffer (f16, first 256B/row)
    const int* __restrict__ slot_cnt,
    const int* __restrict__ slots,
    const float* __restrict__ nbr_fea,
    const float* __restrict__ ln2_g, const float* __restrict__ ln2_b,
    const float* __restrict__ W1a, const float* __restrict__ b1a,
    const float* __restrict__ W2a, const float* __restrict__ b2a,
    const float* __restrict__ W1b, const float* __restrict__ b1b,
    const float* __restrict__ W2b, const float* __restrict__ b2b,
    float* __restrict__ out)
{
    __shared__ unsigned short xb[MT * XBS];    // x (64x128 bf16), running value
    __shared__ unsigned short h1[MT * H1S];    // hidden (64x64 bf16)
    __shared__ unsigned short wl[128 * W2S];   // shared weight buffer (max of W1/W2)

    const int tid  = threadIdx.x;
    const int row0 = blockIdx.x * MT;
    const int w    = tid >> 6, lane = tid & 63;
    const int rl   = lane & 15, kgrp = lane >> 4;

    // ---- phase 0: gather msg rows -> mean -> LN2 -> xb (bf16). 4 threads/edge, 32 feats each.
    {
        int m = tid >> 2;
        int q = tid & 3;
        int e = min(row0 + m, N_EDGES - 1);
        int cnt = min(slot_cnt[e], CAP);
        float v[32];
        #pragma unroll
        for (int i = 0; i < 32; ++i) v[i] = 0.f;
        const char* hb = (const char*)hmsg;
        for (int k = 0; k < cnt; ++k) {
            int r = slots[(size_t)e * CAP + k];
            const uint4* mr = (const uint4*)(hb + (size_t)r * 512 + q * 64);
            #pragma unroll
            for (int t = 0; t < 4; ++t) {
                uint4 u = mr[t];
                unsigned int d[4] = {u.x, u.y, u.z, u.w};
                #pragma unroll
                for (int i2 = 0; i2 < 4; ++i2) {
                    __half2 hh = *reinterpret_cast<__half2*>(&d[i2]);
                    float2 f2 = __half22float2(hh);
                    v[8*t + 2*i2]     += f2.x;
                    v[8*t + 2*i2 + 1] += f2.y;
                }
            }
        }
        float inv = 1.f / fmaxf((float)cnt, 1.f);
        float sum = 0.f, ssq = 0.f;
        #pragma unroll
        for (int i = 0; i < 32; ++i) { v[i] *= inv; sum += v[i]; ssq += v[i] * v[i]; }
        sum += __shfl_xor(sum, 1, 64); ssq += __shfl_xor(ssq, 1, 64);
        sum += __shfl_xor(sum, 2, 64); ssq += __shfl_xor(ssq, 2, 64);
        float mu  = sum * (1.f / 128.f);
        float var = ssq * (1.f / 128.f) - mu * mu;
        float rs  = rsqrtf(var + EPS_LN);
        #pragma unroll
        for (int i = 0; i < 32; ++i) {
            int col = q * 32 + i;
            v[i] = (v[i] - mu) * rs * ln2_g[col] + ln2_b[col];
        }
        #pragma unroll
        for (int t = 0; t < 4; ++t) {
            float4 a = make_float4(v[8*t+0], v[8*t+1], v[8*t+2], v[8*t+3]);
            float4 b = make_float4(v[8*t+4], v[8*t+5], v[8*t+6], v[8*t+7]);
            *(uint4*)&xb[m * XBS + q * 32 + t * 8] = cvt8(a, b);
        }
    }

    const float* W1s[2] = {W1a, W1b};
    const float* B1s[2] = {b1a, b1b};
    const float* W2s[2] = {W2a, W2b};
    const float* B2s[2] = {b2a, b2b};

    #pragma unroll 1
    for (int blk = 0; blk < 2; ++blk) {
        const float* W1 = W1s[blk]; const float* B1 = B1s[blk];
        const float* W2 = W2s[blk]; const float* B2 = B2s[blk];

        // ---- stage W1 (64 x 128) into wl, bf16
        __syncthreads();   // wl free (and phase-0 xb globally visible on blk 0)
        #pragma unroll
        for (int c = tid; c < 1024; c += 256) {
            int nn = c >> 4, kc = c & 15;
            const float* src = W1 + (size_t)nn * 128 + kc * 8;
            *(uint4*)&wl[nn * W1S + kc * 8] =
                cvt8(((const float4*)src)[0], ((const float4*)src)[1]);
        }
        __syncthreads();

        // ---- GEMM1: D1[n=64][m=16/wave] = sum_k W1[n][k] x[m][k], K=128
        short8 xf[4];
        #pragma unroll
        for (int ks = 0; ks < 4; ++ks)
            xf[ks] = *(const short8*)&xb[(w * 16 + rl) * XBS + ks * 32 + kgrp * 8];
        floatx4 a1[4];
        #pragma unroll
        for (int i = 0; i < 4; ++i) {
            a1[i] = (floatx4){0.f, 0.f, 0.f, 0.f};
            #pragma unroll
            for (int ks = 0; ks < 4; ++ks) {
                short8 wf = *(const short8*)&wl[(i * 16 + rl) * W1S + ks * 32 + kgrp * 8];
                a1[i] = __builtin_amdgcn_mfma_f32_16x16x32_bf16(wf, xf[ks], a1[i], 0, 0, 0);
            }
        }
        // silu + bias -> h1[m][n]  (lane: m = w*16+rl, n = i*16 + kgrp*4 + reg)
        #pragma unroll
        for (int i = 0; i < 4; ++i) {
            int nb = i * 16 + kgrp * 4;
            float s0 = a1[i][0] + B1[nb + 0];
            float s1 = a1[i][1] + B1[nb + 1];
            float s2 = a1[i][2] + B1[nb + 2];
            float s3 = a1[i][3] + B1[nb + 3];
            s0 = s0 / (1.f + __expf(-s0));
            s1 = s1 / (1.f + __expf(-s1));
            s2 = s2 / (1.f + __expf(-s2));
            s3 = s3 / (1.f + __expf(-s3));
            unsigned int lo = (unsigned int)f2bf(s0) | ((unsigned int)f2bf(s1) << 16);
            unsigned int hi = (unsigned int)f2bf(s2) | ((unsigned int)f2bf(s3) << 16);
            *(unsigned int*)&h1[(w * 16 + rl) * H1S + nb]     = lo;
            *(unsigned int*)&h1[(w * 16 + rl) * H1S + nb + 2] = hi;
        }

        // ---- stage W2 (128 x 64) into wl (all waves done reading W1)
        __syncthreads();
        #pragma unroll
        for (int c = tid; c < 1024; c += 256) {
            int pp = c >> 3, kc = c & 7;
            const float* src = W2 + (size_t)pp * 64 + kc * 8;
            *(uint4*)&wl[pp * W2S + kc * 8] =
                cvt8(((const float4*)src)[0], ((const float4*)src)[1]);
        }
        __syncthreads();

        // ---- GEMM2: D2[p=128][m=16/wave] = sum_j W2[p][j] h1[m][j], K=64
        short8 hf[2];
        #pragma unroll
        for (int ks = 0; ks < 2; ++ks)
            hf[ks] = *(const short8*)&h1[(w * 16 + rl) * H1S + ks * 32 + kgrp * 8];
        #pragma unroll
        for (int p = 0; p < 8; ++p) {
            floatx4 a2 = (floatx4){0.f, 0.f, 0.f, 0.f};
            #pragma unroll
            for (int ks = 0; ks < 2; ++ks) {
                short8 wf = *(const short8*)&wl[(p * 16 + rl) * W2S + ks * 32 + kgrp * 8];
                a2 = __builtin_amdgcn_mfma_f32_16x16x32_bf16(wf, hf[ks], a2, 0, 0, 0);
            }
            // residual: xb[m][pcol] += a2 + b2   (wave-local rows)
            int m = w * 16 + rl;
            #pragma unroll
            for (int reg = 0; reg < 4; ++reg) {
                int pcol = p * 16 + kgrp * 4 + reg;
                int idx  = m * XBS + pcol;
                float xv = bfbits2f(xb[idx]);
                xb[idx] = f2bf(xv + a2[reg] + B2[pcol]);
            }
        }
    }

    // ---- final: out = INV_SQRT_2 * (nbr_fea + x)   (xb rows wave-local)
    {
        int m = tid >> 2;
        int q = tid & 3;
        int e = row0 + m;
        if (e < N_EDGES) {
            const float4* nf = (const float4*)(nbr_fea + (size_t)e * NF + q * 32);
            float4* dst      = (float4*)(out + (size_t)e * NF + q * 32);
            #pragma unroll
            for (int t = 0; t < 8; ++t) {
                float4 f = nf[t];
                int col = q * 32 + 4 * t;
                dst[t] = make_float4(
                    INV_SQRT_2 * (f.x + bfbits2f(xb[m * XBS + col + 0])),
                    INV_SQRT_2 * (f.y + bfbits2f(xb[m * XBS + col + 1])),
                    INV_SQRT_2 * (f.z + bfbits2f(xb[m * XBS + col + 2])),
                    INV_SQRT_2 * (f.w + bfbits2f(xb[m * XBS + col + 3])));
            }
        }
    }
}

// ---------------- workspace layout (bytes) ----------------
//   [0,         524288)   segSum   (512*256 f32)  -> mean after finalize
//   [524288,   1048576)   segSumSq (512*256 f32)  -> scale after finalize
//   [1048576,  1448576)   slot_cnt (100000 i32)
//   --- everything above zeroed each launch (1.45 MB) ---
//   [1448576,  1450628)   seg_start (513 i32)
//   [1450752, 14250752)   slots (100000*32 i32)
//   [14250752, 219050752) h (400000*256 bf16; msg f16 written in place over first 256B/row)

extern "C" void kernel_launch(void* const* d_in, const int* in_sizes, int n_in,
                              void* d_out, int out_size, void* d_ws, size_t ws_size,
                              hipStream_t stream) {
    const float* nbr_fea       = (const float*)d_in[0];
    const float* angle_fea     = (const float*)d_in[1];
    const int*   angle_nbr_idx = (const int*)d_in[2];
    const int*   cai           = (const int*)d_in[4];
    const float* W_full        = (const float*)d_in[5];
    const float* W_mask        = (const float*)d_in[6];
    const float* cn_gamma      = (const float*)d_in[7];
    const float* cn_beta       = (const float*)d_in[8];
    const float* ln_core_g     = (const float*)d_in[9];
    const float* ln_core_b     = (const float*)d_in[10];
    const float* ln2_g         = (const float*)d_in[11];
    const float* ln2_b         = (const float*)d_in[12];
    const float* W1a           = (const float*)d_in[13];
    const float* b1a           = (const float*)d_in[14];
    const float* W2a           = (const float*)d_in[15];
    const float* b2a           = (const float*)d_in[16];
    const float* W1b           = (const float*)d_in[17];
    const float* b1b           = (const float*)d_in[18];
    const float* W2b           = (const float*)d_in[19];
    const float* b2b           = (const float*)d_in[20];
    float* out = (float*)d_out;

    char* ws = (char*)d_ws;
    float* segSum    = (float*)(ws + 0);
    float* segSumSq  = (float*)(ws + 524288);
    int*   slot_cnt  = (int*)  (ws + 1048576);
    int*   seg_start = (int*)  (ws + 1448576);
    int*   slots     = (int*)  (ws + 1450752);
    __hip_bfloat16* h = (__hip_bfloat16*)(ws + 14250752);

    hipMemsetAsync(ws, 0, 1448576, stream);

    seg_bounds<<<3, 256, 0, stream>>>(cai, seg_start);
    gemm_gather_mfma<<<N_ANGLES / 128, 512, 0, stream>>>(
        angle_fea, nbr_fea, angle_nbr_idx, W_full, cai, segSum, segSumSq, h);
    seg_finalize<<<N_CRYST, 256, 0, stream>>>(seg_start, segSum, segSumSq);
    angle_msg<<<N_ANGLES / 4, 256, 0, stream>>>(
        h, cai, angle_nbr_idx, segSum, segSumSq,
        cn_gamma, cn_beta, ln_core_g, ln_core_b, W_mask, slot_cnt, slots);
    edge_mlp_mfma<<<(N_EDGES + MT - 1) / MT, 256, 0, stream>>>(
        h, slot_cnt, slots, nbr_fea, ln2_g, ln2_b,
        W1a, b1a, W2a, b2a, W1b, b1b, W2b, b2b, out);
}